// Round 5
// baseline (4456.162 us; speedup 1.0000x reference)
//
#include <hip/hip_runtime.h>

#define NV 50000
#define NE 10000
#define NH 512
#define NI_TOT 300000
#define PB 40000   // player boundary for the ws-free fallback path

// C[M,512] = relu(A[M,512] @ B[512,512] + bias[512]) * rowscale[M]
__global__ __launch_bounds__(256) void gemm_relu_scale(
    const float* __restrict__ A, const float* __restrict__ B,
    const float* __restrict__ bias, const float* __restrict__ rowscale,
    float* __restrict__ C, int M)
{
    __shared__ float As[16][68];   // [k][m]; 68 floats = 272B = 17*16B -> float4-aligned rows
    __shared__ float Bs[16][64];   // [k][n]

    const int tid = threadIdx.x;
    const int tx = tid & 15;       // n-quad
    const int ty = tid >> 4;       // m-quad
    const int tileM = blockIdx.y * 64;
    const int col0  = blockIdx.x * 64;

    const int lr  = tid >> 2;        // 0..63 : A row within tile
    const int lk4 = (tid & 3) * 4;   // 0,4,8,12 : A k quad
    const int bc  = tid & 63;        // 0..63 : B col within tile
    const int bk  = tid >> 6;        // 0..3  : B k base

    float acc[4][4] = {};

    for (int k0 = 0; k0 < NH; k0 += 16) {
        const int arow = tileM + lr;
        float4 av = make_float4(0.f, 0.f, 0.f, 0.f);
        if (arow < M)
            av = *reinterpret_cast<const float4*>(&A[(size_t)arow * NH + k0 + lk4]);
        As[lk4 + 0][lr] = av.x;
        As[lk4 + 1][lr] = av.y;
        As[lk4 + 2][lr] = av.z;
        As[lk4 + 3][lr] = av.w;
        #pragma unroll
        for (int jj = 0; jj < 4; ++jj) {
            const int kk = bk + jj * 4;
            Bs[kk][bc] = B[(size_t)(k0 + kk) * NH + col0 + bc];
        }
        __syncthreads();

        #pragma unroll
        for (int kk = 0; kk < 16; ++kk) {
            float4 a = *reinterpret_cast<const float4*>(&As[kk][ty * 4]);
            float4 b = *reinterpret_cast<const float4*>(&Bs[kk][tx * 4]);
            acc[0][0] += a.x * b.x; acc[0][1] += a.x * b.y; acc[0][2] += a.x * b.z; acc[0][3] += a.x * b.w;
            acc[1][0] += a.y * b.x; acc[1][1] += a.y * b.y; acc[1][2] += a.y * b.z; acc[1][3] += a.y * b.w;
            acc[2][0] += a.z * b.x; acc[2][1] += a.z * b.y; acc[2][2] += a.z * b.z; acc[2][3] += a.z * b.w;
            acc[3][0] += a.w * b.x; acc[3][1] += a.w * b.y; acc[3][2] += a.w * b.z; acc[3][3] += a.w * b.w;
        }
        __syncthreads();
    }

    const int rbase = tileM + ty * 4;
    const int cbase = col0 + tx * 4;
    #pragma unroll
    for (int i = 0; i < 4; ++i) {
        const int row = rbase + i;
        if (row < M) {
            const float s = rowscale[row];
            float4 o;
            o.x = fmaxf(acc[i][0] + bias[cbase + 0], 0.f) * s;
            o.y = fmaxf(acc[i][1] + bias[cbase + 1], 0.f) * s;
            o.z = fmaxf(acc[i][2] + bias[cbase + 2], 0.f) * s;
            o.w = fmaxf(acc[i][3] + bias[cbase + 3], 0.f) * s;
            *reinterpret_cast<float4*>(&C[(size_t)row * NH + cbase]) = o;
        }
    }
}

// dst[sidx[i]] += src[gidx[i]] * regw[i]  for incidences whose sidx in [smin,smax)
__global__ __launch_bounds__(256) void scatter_add_kernel(
    const float* __restrict__ src, const int* __restrict__ gidx,
    const int* __restrict__ sidx, const float* __restrict__ regw,
    float* __restrict__ dst, int ni, int smin, int smax, int gmax)
{
    const int i = blockIdx.x * 2 + (threadIdx.x >> 7);
    if (i >= ni) return;
    const int s = sidx[i];
    if (s < smin || s >= smax) return;
    const int g = gidx[i];
    if (g < 0 || g >= gmax) return;           // defensive: no OOB reads ever
    const int c = (threadIdx.x & 127) << 2;   // 0..508
    const float w = regw[i];
    float4 val = *reinterpret_cast<const float4*>(&src[(size_t)g * NH + c]);
    float* d = &dst[(size_t)s * NH + c];
    atomicAdd(d + 0, val.x * w);
    atomicAdd(d + 1, val.y * w);
    atomicAdd(d + 2, val.z * w);
    atomicAdd(d + 3, val.w * w);
}

// Fallback: for incidences with player>=pmin, recompute ev[g] from final e_out
// and scatter-add into out_v. One block per incidence.
__global__ __launch_bounds__(256) void recompute_ev_scatter(
    const float* __restrict__ e_out, const float* __restrict__ W,
    const float* __restrict__ bias, const float* __restrict__ e_weight,
    const int* __restrict__ player_idx, const int* __restrict__ game_idx,
    const float* __restrict__ e_reg_weight, float* __restrict__ out_v, int pmin)
{
    const int i = blockIdx.x;
    const int p = player_idx[i];
    if (p < pmin || p >= NV) return;
    const int g = game_idx[i];
    if (g < 0 || g >= NE) return;
    __shared__ float eg[NH];
    const int t = threadIdx.x;
    eg[t]       = e_out[(size_t)g * NH + t];
    eg[t + 256] = e_out[(size_t)g * NH + t + 256];
    __syncthreads();
    float s0 = 0.f, s1 = 0.f;
    #pragma unroll 4
    for (int k = 0; k < NH; ++k) {
        const float ek = eg[k];
        s0 += ek * W[(size_t)k * NH + t];
        s1 += ek * W[(size_t)k * NH + t + 256];
    }
    const float ew = e_weight[g] * e_reg_weight[i];
    const float v0 = fmaxf(s0 + bias[t], 0.f) * ew;
    const float v1 = fmaxf(s1 + bias[t + 256], 0.f) * ew;
    atomicAdd(&out_v[(size_t)p * NH + t], v0);
    atomicAdd(&out_v[(size_t)p * NH + t + 256], v1);
}

__global__ __launch_bounds__(256) void init_copy(
    const float* __restrict__ src, float* __restrict__ dst, int n4)
{
    const int i = blockIdx.x * 256 + threadIdx.x;
    if (i < n4)
        reinterpret_cast<float4*>(dst)[i] = reinterpret_cast<const float4*>(src)[i];
}

__global__ __launch_bounds__(256) void init_scale_rows(
    const float* __restrict__ src, const float* __restrict__ w,
    float* __restrict__ dst, int n4)
{
    const int i = blockIdx.x * 256 + threadIdx.x;
    if (i >= n4) return;
    const int row = i >> 7;   // (i*4)/512
    const float s = w[row];
    float4 v = reinterpret_cast<const float4*>(src)[i];
    v.x *= s; v.y *= s; v.z *= s; v.w *= s;
    reinterpret_cast<float4*>(dst)[i] = v;
}

__global__ __launch_bounds__(256) void div_rows(
    const float* __restrict__ rs, float* __restrict__ x, int n4)
{
    const int i = blockIdx.x * 256 + threadIdx.x;
    if (i >= n4) return;
    const int row = i >> 7;
    const float inv = 1.0f / rs[row];
    float4 v = reinterpret_cast<float4*>(x)[i];
    v.x *= inv; v.y *= inv; v.z *= inv; v.w *= inv;
    reinterpret_cast<float4*>(x)[i] = v;
}

extern "C" void kernel_launch(void* const* d_in, const int* in_sizes, int n_in,
                              void* d_out, int out_size, void* d_ws, size_t ws_size,
                              hipStream_t stream) {
    const float* v            = (const float*)d_in[0];
    const float* e            = (const float*)d_in[1];
    const int*   player_idx   = (const int*)d_in[2];
    const int*   game_idx     = (const int*)d_in[3];
    // d_in[4] = idx = arange(NI) -> identity gather, unused
    const float* W_v2e        = (const float*)d_in[5];
    const float* W_e2v        = (const float*)d_in[6];
    const float* b_v          = (const float*)d_in[7];
    const float* b_e          = (const float*)d_in[8];

    // Slots 9/10 and 13/14: setup_inputs() dict order and reference() signature
    // order DISAGREE on 13/14 (dict: e_reg_sum,v_reg_sum; sig: v_reg_sum,e_reg_sum).
    // Disambiguate by element count (NV=50000 vs NE=10000) — robust to either.
    const float* a9  = (const float*)d_in[9];
    const float* a10 = (const float*)d_in[10];
    const float* v_weight = (in_sizes[9]  == NV) ? a9  : a10;
    const float* e_weight = (in_sizes[9]  == NV) ? a10 : a9;
    const float* v_reg_weight = (const float*)d_in[11];
    const float* e_reg_weight = (const float*)d_in[12];
    const float* a13 = (const float*)d_in[13];
    const float* a14 = (const float*)d_in[14];
    const float* e_reg_sum = (in_sizes[13] == NE) ? a13 : a14;
    const float* v_reg_sum = (in_sizes[13] == NE) ? a14 : a13;

    float* out_v = (float*)d_out;                       // [NV,512] final v_out
    float* out_e = (float*)d_out + (size_t)NV * NH;     // [NE,512] final e_out

    // ev_w scratch: use d_ws only if provably large enough; otherwise live in
    // out_v rows [PB,NV) (dead ve_w space) and handle players >= PB by recompute.
    const size_t evw_bytes = (size_t)NE * NH * sizeof(float);
    const bool big_ws = (ws_size >= evw_bytes) && (d_ws != nullptr);
    float* ev_w = big_ws ? (float*)d_ws : (out_v + (size_t)PB * NH);
    const int pb = big_ws ? NV : PB;

    const dim3 blk(256);
    const int n4_e = NE * NH / 4;

    // 1. ve_w = relu(v @ W_v2e + b_v) * v_weight -> out_v region (temp, full)
    gemm_relu_scale<<<dim3(NH / 64, (NV + 63) / 64), blk, 0, stream>>>(
        v, W_v2e, b_v, v_weight, out_v, NV);
    // 2. out_e = e
    init_copy<<<(n4_e + 255) / 256, blk, 0, stream>>>(e, out_e, n4_e);
    // 3. out_e[game] += ve_w[player] * v_reg_weight
    scatter_add_kernel<<<(NI_TOT + 1) / 2, blk, 0, stream>>>(
        out_v, player_idx, game_idx, v_reg_weight, out_e, NI_TOT, 0, NE, NV);
    // 4. out_e /= e_reg_sum  (final e_out)
    div_rows<<<(n4_e + 255) / 256, blk, 0, stream>>>(e_reg_sum, out_e, n4_e);
    // 5. ev_w = relu(out_e @ W_e2v + b_e) * e_weight
    gemm_relu_scale<<<dim3(NH / 64, (NE + 63) / 64), blk, 0, stream>>>(
        out_e, W_e2v, b_e, e_weight, ev_w, NE);
    // 6. out_v rows [0,pb) = v * v_weight
    {
        const int n4 = pb * NH / 4;
        init_scale_rows<<<(n4 + 255) / 256, blk, 0, stream>>>(v, v_weight, out_v, n4);
    }
    // 7. out_v[player] += ev_w[game] * e_reg_weight   (players < pb only)
    scatter_add_kernel<<<(NI_TOT + 1) / 2, blk, 0, stream>>>(
        ev_w, game_idx, player_idx, e_reg_weight, out_v, NI_TOT, 0, pb, NE);
    // 8. out_v rows [0,pb) /= v_reg_sum
    {
        const int n4 = pb * NH / 4;
        div_rows<<<(n4 + 255) / 256, blk, 0, stream>>>(v_reg_sum, out_v, n4);
    }
    if (!big_ws) {
        // 9. out_v rows [PB,NV) = v * v_weight  (overwrites ev_w, now dead)
        const int n4t = (NV - PB) * NH / 4;
        init_scale_rows<<<(n4t + 255) / 256, blk, 0, stream>>>(
            v + (size_t)PB * NH, v_weight + PB, out_v + (size_t)PB * NH, n4t);
        // 10. players >= PB: recompute ev rows from final out_e and scatter
        recompute_ev_scatter<<<NI_TOT, blk, 0, stream>>>(
            out_e, W_e2v, b_e, e_weight, player_idx, game_idx, e_reg_weight,
            out_v, PB);
        // 11. out_v rows [PB,NV) /= v_reg_sum
        div_rows<<<(n4t + 255) / 256, blk, 0, stream>>>(
            v_reg_sum + PB, out_v + (size_t)PB * NH, n4t);
    }
}

// Round 6
// 955.734 us; speedup vs baseline: 4.6626x; 4.6626x over previous
//
#include <hip/hip_runtime.h>

#define NV 50000
#define NE 10000
#define NH 512
#define NI_TOT 300000
#define PB 40000   // player boundary for the ws-free fallback path

// ---------------- GEMM: C[M,512] = relu(A @ B + bias) * rowscale ----------------
__global__ __launch_bounds__(256) void gemm_relu_scale(
    const float* __restrict__ A, const float* __restrict__ B,
    const float* __restrict__ bias, const float* __restrict__ rowscale,
    float* __restrict__ C, int M)
{
    __shared__ float As[16][68];
    __shared__ float Bs[16][64];

    const int tid = threadIdx.x;
    const int tx = tid & 15;
    const int ty = tid >> 4;
    const int tileM = blockIdx.y * 64;
    const int col0  = blockIdx.x * 64;

    const int lr  = tid >> 2;
    const int lk4 = (tid & 3) * 4;
    const int bc  = tid & 63;
    const int bk  = tid >> 6;

    float acc[4][4] = {};

    for (int k0 = 0; k0 < NH; k0 += 16) {
        const int arow = tileM + lr;
        float4 av = make_float4(0.f, 0.f, 0.f, 0.f);
        if (arow < M)
            av = *reinterpret_cast<const float4*>(&A[(size_t)arow * NH + k0 + lk4]);
        As[lk4 + 0][lr] = av.x;
        As[lk4 + 1][lr] = av.y;
        As[lk4 + 2][lr] = av.z;
        As[lk4 + 3][lr] = av.w;
        #pragma unroll
        for (int jj = 0; jj < 4; ++jj) {
            const int kk = bk + jj * 4;
            Bs[kk][bc] = B[(size_t)(k0 + kk) * NH + col0 + bc];
        }
        __syncthreads();

        #pragma unroll
        for (int kk = 0; kk < 16; ++kk) {
            float4 a = *reinterpret_cast<const float4*>(&As[kk][ty * 4]);
            float4 b = *reinterpret_cast<const float4*>(&Bs[kk][tx * 4]);
            acc[0][0] += a.x * b.x; acc[0][1] += a.x * b.y; acc[0][2] += a.x * b.z; acc[0][3] += a.x * b.w;
            acc[1][0] += a.y * b.x; acc[1][1] += a.y * b.y; acc[1][2] += a.y * b.z; acc[1][3] += a.y * b.w;
            acc[2][0] += a.z * b.x; acc[2][1] += a.z * b.y; acc[2][2] += a.z * b.z; acc[2][3] += a.z * b.w;
            acc[3][0] += a.w * b.x; acc[3][1] += a.w * b.y; acc[3][2] += a.w * b.z; acc[3][3] += a.w * b.w;
        }
        __syncthreads();
    }

    const int rbase = tileM + ty * 4;
    const int cbase = col0 + tx * 4;
    #pragma unroll
    for (int i = 0; i < 4; ++i) {
        const int row = rbase + i;
        if (row < M) {
            const float s = rowscale[row];
            float4 o;
            o.x = fmaxf(acc[i][0] + bias[cbase + 0], 0.f) * s;
            o.y = fmaxf(acc[i][1] + bias[cbase + 1], 0.f) * s;
            o.z = fmaxf(acc[i][2] + bias[cbase + 2], 0.f) * s;
            o.w = fmaxf(acc[i][3] + bias[cbase + 3], 0.f) * s;
            *reinterpret_cast<float4*>(&C[(size_t)row * NH + cbase]) = o;
        }
    }
}

// ---------------- CSR build ----------------
__global__ __launch_bounds__(256) void zero_ints(int* __restrict__ p, int n)
{
    const int i = blockIdx.x * 256 + threadIdx.x;
    if (i < n) p[i] = 0;
}

__global__ __launch_bounds__(256) void hist_kernel(
    const int* __restrict__ gi, const int* __restrict__ pi,
    int* __restrict__ e_cnt, int* __restrict__ v_cnt)
{
    const int i = blockIdx.x * 256 + threadIdx.x;
    if (i >= NI_TOT) return;
    atomicAdd(&e_cnt[gi[i]], 1);
    atomicAdd(&v_cnt[pi[i]], 1);
}

// exclusive scan: off[0]=0, off[k]=sum(cnt[0..k-1]); single block, 256 threads
__global__ __launch_bounds__(256) void scan_kernel(
    const int* __restrict__ cnt, int* __restrict__ off, int n)
{
    __shared__ int buf[256];
    __shared__ int carry_s;
    const int t = threadIdx.x;
    if (t == 0) { off[0] = 0; carry_s = 0; }
    __syncthreads();
    for (int base = 0; base < n; base += 256) {
        int x = (base + t < n) ? cnt[base + t] : 0;
        buf[t] = x;
        __syncthreads();
        #pragma unroll
        for (int d = 1; d < 256; d <<= 1) {
            int y = (t >= d) ? buf[t - d] : 0;
            __syncthreads();
            buf[t] += y;
            __syncthreads();
        }
        if (base + t < n) off[base + t + 1] = buf[t] + carry_s;
        __syncthreads();
        if (t == 255) carry_s += buf[255];
        __syncthreads();
    }
}

__global__ __launch_bounds__(256) void fill_kernel(
    const int* __restrict__ gi, const int* __restrict__ pi,
    const int* __restrict__ e_off, int* __restrict__ e_cur, int* __restrict__ e_list,
    const int* __restrict__ v_off, int* __restrict__ v_cur, int* __restrict__ v_list)
{
    const int i = blockIdx.x * 256 + threadIdx.x;
    if (i >= NI_TOT) return;
    const int g = gi[i];
    e_list[e_off[g] + atomicAdd(&e_cur[g], 1)] = i;
    const int p = pi[i];
    v_list[v_off[p] + atomicAdd(&v_cur[p], 1)] = i;
}

// ---------------- gather-side aggregation (atomic-free) ----------------
// out_e[g] = (e[g] + sum_i ve_w[player[i]]*v_reg_weight[i]) / e_reg_sum[g]
__global__ __launch_bounds__(128) void agg_e_kernel(
    const float* __restrict__ e, const float* __restrict__ ve_w,
    const int* __restrict__ player_idx, const float* __restrict__ v_reg_weight,
    const int* __restrict__ e_off, const int* __restrict__ e_list,
    const float* __restrict__ e_reg_sum, float* __restrict__ out_e)
{
    const int g = blockIdx.x;
    const int c = threadIdx.x << 2;
    float4 acc = *reinterpret_cast<const float4*>(&e[(size_t)g * NH + c]);
    const int beg = e_off[g], end = e_off[g + 1];
    for (int k = beg; k < end; ++k) {
        const int   i = e_list[k];
        const int   p = player_idx[i];
        const float w = v_reg_weight[i];
        float4 x = *reinterpret_cast<const float4*>(&ve_w[(size_t)p * NH + c]);
        acc.x += w * x.x; acc.y += w * x.y; acc.z += w * x.z; acc.w += w * x.w;
    }
    const float inv = 1.0f / e_reg_sum[g];
    acc.x *= inv; acc.y *= inv; acc.z *= inv; acc.w *= inv;
    *reinterpret_cast<float4*>(&out_e[(size_t)g * NH + c]) = acc;
}

// out_v[p] = (v[p]*v_weight[p] + sum_i ev_w[game[i]]*e_reg_weight[i]) / v_reg_sum[p]
__global__ __launch_bounds__(128) void agg_v_kernel(
    const float* __restrict__ v, const float* __restrict__ v_weight,
    const float* __restrict__ ev_w,
    const int* __restrict__ game_idx, const float* __restrict__ e_reg_weight,
    const int* __restrict__ v_off, const int* __restrict__ v_list,
    const float* __restrict__ v_reg_sum, float* __restrict__ out_v)
{
    const int p = blockIdx.x;
    const int c = threadIdx.x << 2;
    const float vw = v_weight[p];
    float4 acc = *reinterpret_cast<const float4*>(&v[(size_t)p * NH + c]);
    acc.x *= vw; acc.y *= vw; acc.z *= vw; acc.w *= vw;
    const int beg = v_off[p], end = v_off[p + 1];
    for (int k = beg; k < end; ++k) {
        const int   i = v_list[k];
        const int   g = game_idx[i];
        const float w = e_reg_weight[i];
        float4 x = *reinterpret_cast<const float4*>(&ev_w[(size_t)g * NH + c]);
        acc.x += w * x.x; acc.y += w * x.y; acc.z += w * x.z; acc.w += w * x.w;
    }
    const float inv = 1.0f / v_reg_sum[p];
    acc.x *= inv; acc.y *= inv; acc.z *= inv; acc.w *= inv;
    *reinterpret_cast<float4*>(&out_v[(size_t)p * NH + c]) = acc;
}

// ---------------- fallback-path kernels (round-5, passing) ----------------
__global__ __launch_bounds__(256) void scatter_add_kernel(
    const float* __restrict__ src, const int* __restrict__ gidx,
    const int* __restrict__ sidx, const float* __restrict__ regw,
    float* __restrict__ dst, int ni, int smin, int smax, int gmax)
{
    const int i = blockIdx.x * 2 + (threadIdx.x >> 7);
    if (i >= ni) return;
    const int s = sidx[i];
    if (s < smin || s >= smax) return;
    const int g = gidx[i];
    if (g < 0 || g >= gmax) return;
    const int c = (threadIdx.x & 127) << 2;
    const float w = regw[i];
    float4 val = *reinterpret_cast<const float4*>(&src[(size_t)g * NH + c]);
    float* d = &dst[(size_t)s * NH + c];
    atomicAdd(d + 0, val.x * w);
    atomicAdd(d + 1, val.y * w);
    atomicAdd(d + 2, val.z * w);
    atomicAdd(d + 3, val.w * w);
}

__global__ __launch_bounds__(256) void recompute_ev_scatter(
    const float* __restrict__ e_out, const float* __restrict__ W,
    const float* __restrict__ bias, const float* __restrict__ e_weight,
    const int* __restrict__ player_idx, const int* __restrict__ game_idx,
    const float* __restrict__ e_reg_weight, float* __restrict__ out_v, int pmin)
{
    const int i = blockIdx.x;
    const int p = player_idx[i];
    if (p < pmin || p >= NV) return;
    const int g = game_idx[i];
    if (g < 0 || g >= NE) return;
    __shared__ float eg[NH];
    const int t = threadIdx.x;
    eg[t]       = e_out[(size_t)g * NH + t];
    eg[t + 256] = e_out[(size_t)g * NH + t + 256];
    __syncthreads();
    float s0 = 0.f, s1 = 0.f;
    #pragma unroll 4
    for (int k = 0; k < NH; ++k) {
        const float ek = eg[k];
        s0 += ek * W[(size_t)k * NH + t];
        s1 += ek * W[(size_t)k * NH + t + 256];
    }
    const float ew = e_weight[g] * e_reg_weight[i];
    atomicAdd(&out_v[(size_t)p * NH + t],       fmaxf(s0 + bias[t], 0.f) * ew);
    atomicAdd(&out_v[(size_t)p * NH + t + 256], fmaxf(s1 + bias[t + 256], 0.f) * ew);
}

__global__ __launch_bounds__(256) void init_copy(
    const float* __restrict__ src, float* __restrict__ dst, int n4)
{
    const int i = blockIdx.x * 256 + threadIdx.x;
    if (i < n4)
        reinterpret_cast<float4*>(dst)[i] = reinterpret_cast<const float4*>(src)[i];
}

__global__ __launch_bounds__(256) void init_scale_rows(
    const float* __restrict__ src, const float* __restrict__ w,
    float* __restrict__ dst, int n4)
{
    const int i = blockIdx.x * 256 + threadIdx.x;
    if (i >= n4) return;
    const int row = i >> 7;
    const float s = w[row];
    float4 v = reinterpret_cast<const float4*>(src)[i];
    v.x *= s; v.y *= s; v.z *= s; v.w *= s;
    reinterpret_cast<float4*>(dst)[i] = v;
}

__global__ __launch_bounds__(256) void div_rows(
    const float* __restrict__ rs, float* __restrict__ x, int n4)
{
    const int i = blockIdx.x * 256 + threadIdx.x;
    if (i >= n4) return;
    const int row = i >> 7;
    const float inv = 1.0f / rs[row];
    float4 v = reinterpret_cast<float4*>(x)[i];
    v.x *= inv; v.y *= inv; v.z *= inv; v.w *= inv;
    reinterpret_cast<float4*>(x)[i] = v;
}

extern "C" void kernel_launch(void* const* d_in, const int* in_sizes, int n_in,
                              void* d_out, int out_size, void* d_ws, size_t ws_size,
                              hipStream_t stream) {
    const float* v            = (const float*)d_in[0];
    const float* e            = (const float*)d_in[1];
    const int*   player_idx   = (const int*)d_in[2];
    const int*   game_idx     = (const int*)d_in[3];
    // d_in[4] = idx = arange(NI), identity gather -> unused
    const float* W_v2e        = (const float*)d_in[5];
    const float* W_e2v        = (const float*)d_in[6];
    const float* b_v          = (const float*)d_in[7];
    const float* b_e          = (const float*)d_in[8];

    // disambiguate by element count (robust to dict-vs-signature marshalling order)
    const float* a9  = (const float*)d_in[9];
    const float* a10 = (const float*)d_in[10];
    const float* v_weight = (in_sizes[9]  == NV) ? a9  : a10;
    const float* e_weight = (in_sizes[9]  == NV) ? a10 : a9;
    const float* v_reg_weight = (const float*)d_in[11];
    const float* e_reg_weight = (const float*)d_in[12];
    const float* a13 = (const float*)d_in[13];
    const float* a14 = (const float*)d_in[14];
    const float* e_reg_sum = (in_sizes[13] == NE) ? a13 : a14;
    const float* v_reg_sum = (in_sizes[13] == NE) ? a14 : a13;

    float* out_v = (float*)d_out;                       // [NV,512]
    float* out_e = (float*)d_out + (size_t)NV * NH;     // [NE,512]

    const dim3 blk(256);

    // ---- workspace layout for the CSR path ----
    float* ev_w = (float*)d_ws;                             // [NE*NH] floats
    int* ibase  = (int*)((char*)d_ws + (size_t)NE * NH * sizeof(float));
    int* e_cnt  = ibase;
    int* v_cnt  = e_cnt + NE;
    int* e_cur  = v_cnt + NV;
    int* v_cur  = e_cur + NE;
    int* e_off  = v_cur + NV;           // NE+1
    int* v_off  = e_off + NE + 1;       // NV+1
    int* e_list = v_off + NV + 1;       // NI
    int* v_list = e_list + NI_TOT;      // NI
    const size_t csr_need = (size_t)((char*)(v_list + NI_TOT) - (char*)d_ws);

    if (ws_size >= csr_need && d_ws != nullptr) {
        // ---------- CSR path (atomic-free aggregation) ----------
        // 1. ve_w = relu(v@W_v2e+b_v)*v_weight -> out_v (temp)
        gemm_relu_scale<<<dim3(NH / 64, (NV + 63) / 64), blk, 0, stream>>>(
            v, W_v2e, b_v, v_weight, out_v, NV);
        // 2. CSR build (overlaps nothing; ~tens of us)
        const int nz = 2 * (NE + NV);
        zero_ints<<<(nz + 255) / 256, blk, 0, stream>>>(e_cnt, nz);
        hist_kernel<<<(NI_TOT + 255) / 256, blk, 0, stream>>>(
            game_idx, player_idx, e_cnt, v_cnt);
        scan_kernel<<<1, blk, 0, stream>>>(e_cnt, e_off, NE);
        scan_kernel<<<1, blk, 0, stream>>>(v_cnt, v_off, NV);
        fill_kernel<<<(NI_TOT + 255) / 256, blk, 0, stream>>>(
            game_idx, player_idx, e_off, e_cur, e_list, v_off, v_cur, v_list);
        // 3. out_e = (e + gather-sum) / e_reg_sum   (final)
        agg_e_kernel<<<NE, dim3(128), 0, stream>>>(
            e, out_v, player_idx, v_reg_weight, e_off, e_list, e_reg_sum, out_e);
        // 4. ev_w = relu(out_e@W_e2v+b_e)*e_weight -> ws
        gemm_relu_scale<<<dim3(NH / 64, (NE + 63) / 64), blk, 0, stream>>>(
            out_e, W_e2v, b_e, e_weight, ev_w, NE);
        // 5. out_v = (v*v_weight + gather-sum) / v_reg_sum   (final)
        agg_v_kernel<<<NV, dim3(128), 0, stream>>>(
            v, v_weight, ev_w, game_idx, e_reg_weight, v_off, v_list,
            v_reg_sum, out_v);
        return;
    }

    // ---------- fallback: round-5 atomic path (known-passing) ----------
    const size_t evw_bytes = (size_t)NE * NH * sizeof(float);
    const bool big_ws = (ws_size >= evw_bytes) && (d_ws != nullptr);
    float* ev_w2 = big_ws ? (float*)d_ws : (out_v + (size_t)PB * NH);
    const int pb = big_ws ? NV : PB;
    const int n4_e = NE * NH / 4;

    gemm_relu_scale<<<dim3(NH / 64, (NV + 63) / 64), blk, 0, stream>>>(
        v, W_v2e, b_v, v_weight, out_v, NV);
    init_copy<<<(n4_e + 255) / 256, blk, 0, stream>>>(e, out_e, n4_e);
    scatter_add_kernel<<<(NI_TOT + 1) / 2, blk, 0, stream>>>(
        out_v, player_idx, game_idx, v_reg_weight, out_e, NI_TOT, 0, NE, NV);
    div_rows<<<(n4_e + 255) / 256, blk, 0, stream>>>(e_reg_sum, out_e, n4_e);
    gemm_relu_scale<<<dim3(NH / 64, (NE + 63) / 64), blk, 0, stream>>>(
        out_e, W_e2v, b_e, e_weight, ev_w2, NE);
    {
        const int n4 = pb * NH / 4;
        init_scale_rows<<<(n4 + 255) / 256, blk, 0, stream>>>(v, v_weight, out_v, n4);
    }
    scatter_add_kernel<<<(NI_TOT + 1) / 2, blk, 0, stream>>>(
        ev_w2, game_idx, player_idx, e_reg_weight, out_v, NI_TOT, 0, pb, NE);
    {
        const int n4 = pb * NH / 4;
        div_rows<<<(n4 + 255) / 256, blk, 0, stream>>>(v_reg_sum, out_v, n4);
    }
    if (!big_ws) {
        const int n4t = (NV - PB) * NH / 4;
        init_scale_rows<<<(n4t + 255) / 256, blk, 0, stream>>>(
            v + (size_t)PB * NH, v_weight + PB, out_v + (size_t)PB * NH, n4t);
        recompute_ev_scatter<<<NI_TOT, blk, 0, stream>>>(
            out_e, W_e2v, b_e, e_weight, player_idx, game_idx, e_reg_weight,
            out_v, PB);
        div_rows<<<(n4t + 255) / 256, blk, 0, stream>>>(
            v_reg_sum + PB, out_v + (size_t)PB * NH, n4t);
    }
}

// Round 7
// 685.502 us; speedup vs baseline: 6.5006x; 1.3942x over previous
//
#include <hip/hip_runtime.h>

#define NV 50000
#define NE 10000
#define NH 512
#define NI_TOT 300000
#define PB 40000

typedef __attribute__((ext_vector_type(8))) short short8v;   // 8 bf16
typedef __attribute__((ext_vector_type(4))) float f32x4;

__device__ __forceinline__ unsigned short f2bf(float x) {
    union { float f; unsigned int u; } v; v.f = x;
    unsigned int r = (v.u + 0x7FFFu + ((v.u >> 16) & 1u)) >> 16;   // RNE
    return (unsigned short)r;
}

// ---------------- MFMA GEMM: C[M,512] = relu(A@B + bias) * rowscale ----------------
// A: [M][512] f32 (cast inline). Bt: [512 n][512 k] bf16 (pre-transposed W).
__global__ __launch_bounds__(256) void gemm_mfma_relu_scale(
    const float* __restrict__ A, const unsigned short* __restrict__ Bt,
    const float* __restrict__ bias, const float* __restrict__ rowscale,
    float* __restrict__ C, int M)
{
    __shared__ unsigned short As[128][72];   // 144B row stride: bank-stride 4 -> 2-way (free)
    __shared__ unsigned short Bs[128][72];

    const int tid  = threadIdx.x;
    const int lane = tid & 63;
    const int wave = tid >> 6;          // 0..3
    const int wm   = (wave & 1) * 64;
    const int wn   = (wave >> 1) * 64;
    const int tileM = blockIdx.y * 128;
    const int col0  = blockIdx.x * 128;

    f32x4 acc[4][4] = {};               // [mf][nf]

    for (int k0 = 0; k0 < NH; k0 += 64) {
        // stage A: 128 rows x 64 k, f32 -> bf16. 8 iters x 256 thr x float4
        #pragma unroll
        for (int j = 0; j < 8; ++j) {
            const int r = j * 16 + (tid >> 4);
            const int c = (tid & 15) * 4;
            const int arow = tileM + r;
            float4 av = make_float4(0.f, 0.f, 0.f, 0.f);
            if (arow < M)
                av = *reinterpret_cast<const float4*>(&A[(size_t)arow * NH + k0 + c]);
            unsigned short* dst = &As[r][c];
            dst[0] = f2bf(av.x); dst[1] = f2bf(av.y);
            dst[2] = f2bf(av.z); dst[3] = f2bf(av.w);
        }
        // stage Bt tile: 128 n x 64 k bf16 = 1024 16B chunks; 4 iters x 256 thr
        #pragma unroll
        for (int j = 0; j < 4; ++j) {
            const int chunk = j * 256 + tid;
            const int n  = chunk >> 3;
            const int kc = (chunk & 7) * 8;
            short8v b = *reinterpret_cast<const short8v*>(
                &Bt[(size_t)(col0 + n) * NH + k0 + kc]);
            *reinterpret_cast<short8v*>(&Bs[n][kc]) = b;
        }
        __syncthreads();

        #pragma unroll
        for (int ks = 0; ks < 2; ++ks) {
            const int koff = ks * 32 + (lane >> 4) * 8;
            short8v af[4], bfr[4];
            #pragma unroll
            for (int mf = 0; mf < 4; ++mf)
                af[mf] = *reinterpret_cast<short8v*>(&As[wm + mf * 16 + (lane & 15)][koff]);
            #pragma unroll
            for (int nf = 0; nf < 4; ++nf)
                bfr[nf] = *reinterpret_cast<short8v*>(&Bs[wn + nf * 16 + (lane & 15)][koff]);
            #pragma unroll
            for (int mf = 0; mf < 4; ++mf)
                #pragma unroll
                for (int nf = 0; nf < 4; ++nf)
                    acc[mf][nf] = __builtin_amdgcn_mfma_f32_16x16x32_bf16(
                        af[mf], bfr[nf], acc[mf][nf], 0, 0, 0);
        }
        __syncthreads();
    }

    // epilogue: C/D layout col=lane&15, row=(lane>>4)*4+reg
    const int rgrp = (lane >> 4) * 4;
    const int cin  = lane & 15;
    #pragma unroll
    for (int mf = 0; mf < 4; ++mf) {
        #pragma unroll
        for (int r = 0; r < 4; ++r) {
            const int row = tileM + wm + mf * 16 + rgrp + r;
            if (row < M) {
                const float rs = rowscale[row];
                #pragma unroll
                for (int nf = 0; nf < 4; ++nf) {
                    const int col = col0 + wn + nf * 16 + cin;
                    C[(size_t)row * NH + col] = fmaxf(acc[mf][nf][r] + bias[col], 0.f) * rs;
                }
            }
        }
    }
}

// Wt[n][k] = bf16(W[k][n]) — one-time 512x512 transpose+cast
__global__ __launch_bounds__(256) void transpose_cast_w(
    const float* __restrict__ W, unsigned short* __restrict__ Wt)
{
    __shared__ float t[32][33];
    const int bx = blockIdx.x;          // n tile
    const int by = blockIdx.y;          // k tile
    const int tx = threadIdx.x & 31;
    const int ty = threadIdx.x >> 5;    // 0..7
    #pragma unroll
    for (int j = 0; j < 32; j += 8)
        t[ty + j][tx] = W[(size_t)(by * 32 + ty + j) * NH + bx * 32 + tx];
    __syncthreads();
    #pragma unroll
    for (int j = 0; j < 32; j += 8)
        Wt[(size_t)(bx * 32 + ty + j) * NH + by * 32 + tx] = f2bf(t[tx][ty + j]);
}

// ---------------- f32 GEMM (fallback paths) ----------------
__global__ __launch_bounds__(256) void gemm_relu_scale(
    const float* __restrict__ A, const float* __restrict__ B,
    const float* __restrict__ bias, const float* __restrict__ rowscale,
    float* __restrict__ C, int M)
{
    __shared__ float As[16][68];
    __shared__ float Bs[16][64];
    const int tid = threadIdx.x;
    const int tx = tid & 15;
    const int ty = tid >> 4;
    const int tileM = blockIdx.y * 64;
    const int col0  = blockIdx.x * 64;
    const int lr  = tid >> 2;
    const int lk4 = (tid & 3) * 4;
    const int bc  = tid & 63;
    const int bk  = tid >> 6;
    float acc[4][4] = {};
    for (int k0 = 0; k0 < NH; k0 += 16) {
        const int arow = tileM + lr;
        float4 av = make_float4(0.f, 0.f, 0.f, 0.f);
        if (arow < M)
            av = *reinterpret_cast<const float4*>(&A[(size_t)arow * NH + k0 + lk4]);
        As[lk4 + 0][lr] = av.x; As[lk4 + 1][lr] = av.y;
        As[lk4 + 2][lr] = av.z; As[lk4 + 3][lr] = av.w;
        #pragma unroll
        for (int jj = 0; jj < 4; ++jj) {
            const int kk = bk + jj * 4;
            Bs[kk][bc] = B[(size_t)(k0 + kk) * NH + col0 + bc];
        }
        __syncthreads();
        #pragma unroll
        for (int kk = 0; kk < 16; ++kk) {
            float4 a = *reinterpret_cast<const float4*>(&As[kk][ty * 4]);
            float4 b = *reinterpret_cast<const float4*>(&Bs[kk][tx * 4]);
            acc[0][0] += a.x * b.x; acc[0][1] += a.x * b.y; acc[0][2] += a.x * b.z; acc[0][3] += a.x * b.w;
            acc[1][0] += a.y * b.x; acc[1][1] += a.y * b.y; acc[1][2] += a.y * b.z; acc[1][3] += a.y * b.w;
            acc[2][0] += a.z * b.x; acc[2][1] += a.z * b.y; acc[2][2] += a.z * b.z; acc[2][3] += a.z * b.w;
            acc[3][0] += a.w * b.x; acc[3][1] += a.w * b.y; acc[3][2] += a.w * b.z; acc[3][3] += a.w * b.w;
        }
        __syncthreads();
    }
    const int rbase = tileM + ty * 4;
    const int cbase = col0 + tx * 4;
    #pragma unroll
    for (int i = 0; i < 4; ++i) {
        const int row = rbase + i;
        if (row < M) {
            const float s = rowscale[row];
            float4 o;
            o.x = fmaxf(acc[i][0] + bias[cbase + 0], 0.f) * s;
            o.y = fmaxf(acc[i][1] + bias[cbase + 1], 0.f) * s;
            o.z = fmaxf(acc[i][2] + bias[cbase + 2], 0.f) * s;
            o.w = fmaxf(acc[i][3] + bias[cbase + 3], 0.f) * s;
            *reinterpret_cast<float4*>(&C[(size_t)row * NH + cbase]) = o;
        }
    }
}

// ---------------- CSR build ----------------
__global__ __launch_bounds__(256) void zero_ints(int* __restrict__ p, int n)
{
    const int i = blockIdx.x * 256 + threadIdx.x;
    if (i < n) p[i] = 0;
}

__global__ __launch_bounds__(256) void hist_kernel(
    const int* __restrict__ gi, const int* __restrict__ pi,
    int* __restrict__ e_cnt, int* __restrict__ v_cnt)
{
    const int i = blockIdx.x * 256 + threadIdx.x;
    if (i >= NI_TOT) return;
    atomicAdd(&e_cnt[gi[i]], 1);
    atomicAdd(&v_cnt[pi[i]], 1);
}

__global__ __launch_bounds__(256) void scan_kernel(
    const int* __restrict__ cnt, int* __restrict__ off, int n)
{
    __shared__ int buf[256];
    __shared__ int carry_s;
    const int t = threadIdx.x;
    if (t == 0) { off[0] = 0; carry_s = 0; }
    __syncthreads();
    for (int base = 0; base < n; base += 256) {
        int x = (base + t < n) ? cnt[base + t] : 0;
        buf[t] = x;
        __syncthreads();
        #pragma unroll
        for (int d = 1; d < 256; d <<= 1) {
            int y = (t >= d) ? buf[t - d] : 0;
            __syncthreads();
            buf[t] += y;
            __syncthreads();
        }
        if (base + t < n) off[base + t + 1] = buf[t] + carry_s;
        __syncthreads();
        if (t == 255) carry_s += buf[255];
        __syncthreads();
    }
}

__global__ __launch_bounds__(256) void fill_kernel(
    const int* __restrict__ gi, const int* __restrict__ pi,
    const int* __restrict__ e_off, int* __restrict__ e_cur, int* __restrict__ e_list,
    const int* __restrict__ v_off, int* __restrict__ v_cur, int* __restrict__ v_list)
{
    const int i = blockIdx.x * 256 + threadIdx.x;
    if (i >= NI_TOT) return;
    const int g = gi[i];
    e_list[e_off[g] + atomicAdd(&e_cur[g], 1)] = i;
    const int p = pi[i];
    v_list[v_off[p] + atomicAdd(&v_cur[p], 1)] = i;
}

// ---------------- gather-side aggregation ----------------
__global__ __launch_bounds__(128) void agg_e_kernel(
    const float* __restrict__ e, const float* __restrict__ ve_w,
    const int* __restrict__ player_idx, const float* __restrict__ v_reg_weight,
    const int* __restrict__ e_off, const int* __restrict__ e_list,
    const float* __restrict__ e_reg_sum, float* __restrict__ out_e)
{
    const int g = blockIdx.x;
    const int c = threadIdx.x << 2;
    float4 acc = *reinterpret_cast<const float4*>(&e[(size_t)g * NH + c]);
    const int beg = e_off[g], end = e_off[g + 1];
    for (int k = beg; k < end; ++k) {
        const int   i = e_list[k];
        const int   p = player_idx[i];
        const float w = v_reg_weight[i];
        float4 x = *reinterpret_cast<const float4*>(&ve_w[(size_t)p * NH + c]);
        acc.x += w * x.x; acc.y += w * x.y; acc.z += w * x.z; acc.w += w * x.w;
    }
    const float inv = 1.0f / e_reg_sum[g];
    acc.x *= inv; acc.y *= inv; acc.z *= inv; acc.w *= inv;
    *reinterpret_cast<float4*>(&out_e[(size_t)g * NH + c]) = acc;
}

__global__ __launch_bounds__(128) void agg_v_kernel(
    const float* __restrict__ v, const float* __restrict__ v_weight,
    const float* __restrict__ ev_w,
    const int* __restrict__ game_idx, const float* __restrict__ e_reg_weight,
    const int* __restrict__ v_off, const int* __restrict__ v_list,
    const float* __restrict__ v_reg_sum, float* __restrict__ out_v)
{
    const int p = blockIdx.x;
    const int c = threadIdx.x << 2;
    const float vw = v_weight[p];
    float4 acc = *reinterpret_cast<const float4*>(&v[(size_t)p * NH + c]);
    acc.x *= vw; acc.y *= vw; acc.z *= vw; acc.w *= vw;
    const int beg = v_off[p], end = v_off[p + 1];
    for (int k = beg; k < end; ++k) {
        const int   i = v_list[k];
        const int   g = game_idx[i];
        const float w = e_reg_weight[i];
        float4 x = *reinterpret_cast<const float4*>(&ev_w[(size_t)g * NH + c]);
        acc.x += w * x.x; acc.y += w * x.y; acc.z += w * x.z; acc.w += w * x.w;
    }
    const float inv = 1.0f / v_reg_sum[p];
    acc.x *= inv; acc.y *= inv; acc.z *= inv; acc.w *= inv;
    *reinterpret_cast<float4*>(&out_v[(size_t)p * NH + c]) = acc;
}

// ---------------- atomic-path fallback kernels ----------------
__global__ __launch_bounds__(256) void scatter_add_kernel(
    const float* __restrict__ src, const int* __restrict__ gidx,
    const int* __restrict__ sidx, const float* __restrict__ regw,
    float* __restrict__ dst, int ni, int smin, int smax, int gmax)
{
    const int i = blockIdx.x * 2 + (threadIdx.x >> 7);
    if (i >= ni) return;
    const int s = sidx[i];
    if (s < smin || s >= smax) return;
    const int g = gidx[i];
    if (g < 0 || g >= gmax) return;
    const int c = (threadIdx.x & 127) << 2;
    const float w = regw[i];
    float4 val = *reinterpret_cast<const float4*>(&src[(size_t)g * NH + c]);
    float* d = &dst[(size_t)s * NH + c];
    atomicAdd(d + 0, val.x * w);
    atomicAdd(d + 1, val.y * w);
    atomicAdd(d + 2, val.z * w);
    atomicAdd(d + 3, val.w * w);
}

__global__ __launch_bounds__(256) void recompute_ev_scatter(
    const float* __restrict__ e_out, const float* __restrict__ W,
    const float* __restrict__ bias, const float* __restrict__ e_weight,
    const int* __restrict__ player_idx, const int* __restrict__ game_idx,
    const float* __restrict__ e_reg_weight, float* __restrict__ out_v, int pmin)
{
    const int i = blockIdx.x;
    const int p = player_idx[i];
    if (p < pmin || p >= NV) return;
    const int g = game_idx[i];
    if (g < 0 || g >= NE) return;
    __shared__ float eg[NH];
    const int t = threadIdx.x;
    eg[t]       = e_out[(size_t)g * NH + t];
    eg[t + 256] = e_out[(size_t)g * NH + t + 256];
    __syncthreads();
    float s0 = 0.f, s1 = 0.f;
    #pragma unroll 4
    for (int k = 0; k < NH; ++k) {
        const float ek = eg[k];
        s0 += ek * W[(size_t)k * NH + t];
        s1 += ek * W[(size_t)k * NH + t + 256];
    }
    const float ew = e_weight[g] * e_reg_weight[i];
    atomicAdd(&out_v[(size_t)p * NH + t],       fmaxf(s0 + bias[t], 0.f) * ew);
    atomicAdd(&out_v[(size_t)p * NH + t + 256], fmaxf(s1 + bias[t + 256], 0.f) * ew);
}

__global__ __launch_bounds__(256) void init_copy(
    const float* __restrict__ src, float* __restrict__ dst, int n4)
{
    const int i = blockIdx.x * 256 + threadIdx.x;
    if (i < n4)
        reinterpret_cast<float4*>(dst)[i] = reinterpret_cast<const float4*>(src)[i];
}

__global__ __launch_bounds__(256) void init_scale_rows(
    const float* __restrict__ src, const float* __restrict__ w,
    float* __restrict__ dst, int n4)
{
    const int i = blockIdx.x * 256 + threadIdx.x;
    if (i >= n4) return;
    const int row = i >> 7;
    const float s = w[row];
    float4 v = reinterpret_cast<const float4*>(src)[i];
    v.x *= s; v.y *= s; v.z *= s; v.w *= s;
    reinterpret_cast<float4*>(dst)[i] = v;
}

__global__ __launch_bounds__(256) void div_rows(
    const float* __restrict__ rs, float* __restrict__ x, int n4)
{
    const int i = blockIdx.x * 256 + threadIdx.x;
    if (i >= n4) return;
    const int row = i >> 7;
    const float inv = 1.0f / rs[row];
    float4 v = reinterpret_cast<float4*>(x)[i];
    v.x *= inv; v.y *= inv; v.z *= inv; v.w *= inv;
    reinterpret_cast<float4*>(x)[i] = v;
}

extern "C" void kernel_launch(void* const* d_in, const int* in_sizes, int n_in,
                              void* d_out, int out_size, void* d_ws, size_t ws_size,
                              hipStream_t stream) {
    const float* v            = (const float*)d_in[0];
    const float* e            = (const float*)d_in[1];
    const int*   player_idx   = (const int*)d_in[2];
    const int*   game_idx     = (const int*)d_in[3];
    const float* W_v2e        = (const float*)d_in[5];
    const float* W_e2v        = (const float*)d_in[6];
    const float* b_v          = (const float*)d_in[7];
    const float* b_e          = (const float*)d_in[8];

    const float* a9  = (const float*)d_in[9];
    const float* a10 = (const float*)d_in[10];
    const float* v_weight = (in_sizes[9]  == NV) ? a9  : a10;
    const float* e_weight = (in_sizes[9]  == NV) ? a10 : a9;
    const float* v_reg_weight = (const float*)d_in[11];
    const float* e_reg_weight = (const float*)d_in[12];
    const float* a13 = (const float*)d_in[13];
    const float* a14 = (const float*)d_in[14];
    const float* e_reg_sum = (in_sizes[13] == NE) ? a13 : a14;
    const float* v_reg_sum = (in_sizes[13] == NE) ? a14 : a13;

    float* out_v = (float*)d_out;
    float* out_e = (float*)d_out + (size_t)NV * NH;

    const dim3 blk(256);

    // ---- ws layout ----
    float* ev_w = (float*)d_ws;
    int* e_cnt  = (int*)((char*)d_ws + (size_t)NE * NH * sizeof(float));
    int* v_cnt  = e_cnt + NE;
    int* e_cur  = v_cnt + NV;
    int* v_cur  = e_cur + NE;
    int* e_off  = v_cur + NV;
    int* v_off  = e_off + NE + 1;
    int* e_list = v_off + NV + 1;
    int* v_list = e_list + NI_TOT;
    unsigned short* Wt1 = (unsigned short*)(v_list + NI_TOT);   // [512][512] bf16
    unsigned short* Wt2 = Wt1 + (size_t)NH * NH;
    const size_t csr_need  = (size_t)((char*)(v_list + NI_TOT) - (char*)d_ws);
    const size_t mfma_need = (size_t)((char*)(Wt2 + (size_t)NH * NH) - (char*)d_ws);

    if (ws_size >= mfma_need && d_ws != nullptr) {
        // ---------- bf16-MFMA + CSR path ----------
        transpose_cast_w<<<dim3(16, 16), blk, 0, stream>>>(W_v2e, Wt1);
        transpose_cast_w<<<dim3(16, 16), blk, 0, stream>>>(W_e2v, Wt2);
        const int nz = 2 * (NE + NV);
        zero_ints<<<(nz + 255) / 256, blk, 0, stream>>>(e_cnt, nz);
        hist_kernel<<<(NI_TOT + 255) / 256, blk, 0, stream>>>(
            game_idx, player_idx, e_cnt, v_cnt);
        scan_kernel<<<1, blk, 0, stream>>>(e_cnt, e_off, NE);
        scan_kernel<<<1, blk, 0, stream>>>(v_cnt, v_off, NV);
        fill_kernel<<<(NI_TOT + 255) / 256, blk, 0, stream>>>(
            game_idx, player_idx, e_off, e_cur, e_list, v_off, v_cur, v_list);
        // ve_w -> out_v (temp)
        gemm_mfma_relu_scale<<<dim3(NH / 128, (NV + 127) / 128), blk, 0, stream>>>(
            v, Wt1, b_v, v_weight, out_v, NV);
        agg_e_kernel<<<NE, dim3(128), 0, stream>>>(
            e, out_v, player_idx, v_reg_weight, e_off, e_list, e_reg_sum, out_e);
        gemm_mfma_relu_scale<<<dim3(NH / 128, (NE + 127) / 128), blk, 0, stream>>>(
            out_e, Wt2, b_e, e_weight, ev_w, NE);
        agg_v_kernel<<<NV, dim3(128), 0, stream>>>(
            v, v_weight, ev_w, game_idx, e_reg_weight, v_off, v_list,
            v_reg_sum, out_v);
        return;
    }

    if (ws_size >= csr_need && d_ws != nullptr) {
        // ---------- f32 + CSR path (round-6, known-passing) ----------
        gemm_relu_scale<<<dim3(NH / 64, (NV + 63) / 64), blk, 0, stream>>>(
            v, W_v2e, b_v, v_weight, out_v, NV);
        const int nz = 2 * (NE + NV);
        zero_ints<<<(nz + 255) / 256, blk, 0, stream>>>(e_cnt, nz);
        hist_kernel<<<(NI_TOT + 255) / 256, blk, 0, stream>>>(
            game_idx, player_idx, e_cnt, v_cnt);
        scan_kernel<<<1, blk, 0, stream>>>(e_cnt, e_off, NE);
        scan_kernel<<<1, blk, 0, stream>>>(v_cnt, v_off, NV);
        fill_kernel<<<(NI_TOT + 255) / 256, blk, 0, stream>>>(
            game_idx, player_idx, e_off, e_cur, e_list, v_off, v_cur, v_list);
        agg_e_kernel<<<NE, dim3(128), 0, stream>>>(
            e, out_v, player_idx, v_reg_weight, e_off, e_list, e_reg_sum, out_e);
        gemm_relu_scale<<<dim3(NH / 64, (NE + 63) / 64), blk, 0, stream>>>(
            out_e, W_e2v, b_e, e_weight, ev_w, NE);
        agg_v_kernel<<<NV, dim3(128), 0, stream>>>(
            v, v_weight, ev_w, game_idx, e_reg_weight, v_off, v_list,
            v_reg_sum, out_v);
        return;
    }

    // ---------- atomic fallback (round-5, known-passing) ----------
    const size_t evw_bytes = (size_t)NE * NH * sizeof(float);
    const bool big_ws = (ws_size >= evw_bytes) && (d_ws != nullptr);
    float* ev_w2 = big_ws ? (float*)d_ws : (out_v + (size_t)PB * NH);
    const int pb = big_ws ? NV : PB;
    const int n4_e = NE * NH / 4;

    gemm_relu_scale<<<dim3(NH / 64, (NV + 63) / 64), blk, 0, stream>>>(
        v, W_v2e, b_v, v_weight, out_v, NV);
    init_copy<<<(n4_e + 255) / 256, blk, 0, stream>>>(e, out_e, n4_e);
    scatter_add_kernel<<<(NI_TOT + 1) / 2, blk, 0, stream>>>(
        out_v, player_idx, game_idx, v_reg_weight, out_e, NI_TOT, 0, NE, NV);
    div_rows<<<(n4_e + 255) / 256, blk, 0, stream>>>(e_reg_sum, out_e, n4_e);
    gemm_relu_scale<<<dim3(NH / 64, (NE + 63) / 64), blk, 0, stream>>>(
        out_e, W_e2v, b_e, e_weight, ev_w2, NE);
    {
        const int n4 = pb * NH / 4;
        init_scale_rows<<<(n4 + 255) / 256, blk, 0, stream>>>(v, v_weight, out_v, n4);
    }
    scatter_add_kernel<<<(NI_TOT + 1) / 2, blk, 0, stream>>>(
        ev_w2, game_idx, player_idx, e_reg_weight, out_v, NI_TOT, 0, pb, NE);
    {
        const int n4 = pb * NH / 4;
        div_rows<<<(n4 + 255) / 256, blk, 0, stream>>>(v_reg_sum, out_v, n4);
    }
    if (!big_ws) {
        const int n4t = (NV - PB) * NH / 4;
        init_scale_rows<<<(n4t + 255) / 256, blk, 0, stream>>>(
            v + (size_t)PB * NH, v_weight + PB, out_v + (size_t)PB * NH, n4t);
        recompute_ev_scatter<<<NI_TOT, blk, 0, stream>>>(
            out_e, W_e2v, b_e, e_weight, player_idx, game_idx, e_reg_weight,
            out_v, PB);
        div_rows<<<(n4t + 255) / 256, blk, 0, stream>>>(
            v_reg_sum + PB, out_v + (size_t)PB * NH, n4t);
    }
}

// Round 8
// 446.127 us; speedup vs baseline: 9.9886x; 1.5366x over previous
//
#include <hip/hip_runtime.h>

#define NV 50000
#define NE 10000
#define NH 512
#define NI_TOT 300000
#define PB 40000

typedef __attribute__((ext_vector_type(8))) short short8v;   // 8 bf16
typedef __attribute__((ext_vector_type(4))) float f32x4;

__device__ __forceinline__ unsigned short f2bf(float x) {
    union { float f; unsigned int u; } v; v.f = x;
    unsigned int r = (v.u + 0x7FFFu + ((v.u >> 16) & 1u)) >> 16;   // RNE
    return (unsigned short)r;
}

// ---------------- MFMA GEMM: C[M,512] = relu(A@B + bias) * rowscale ----------------
__global__ __launch_bounds__(256) void gemm_mfma_relu_scale(
    const float* __restrict__ A, const unsigned short* __restrict__ Bt,
    const float* __restrict__ bias, const float* __restrict__ rowscale,
    float* __restrict__ C, int M)
{
    __shared__ unsigned short As[128][72];
    __shared__ unsigned short Bs[128][72];

    const int tid  = threadIdx.x;
    const int lane = tid & 63;
    const int wave = tid >> 6;
    const int wm   = (wave & 1) * 64;
    const int wn   = (wave >> 1) * 64;
    const int tileM = blockIdx.y * 128;
    const int col0  = blockIdx.x * 128;

    f32x4 acc[4][4] = {};

    for (int k0 = 0; k0 < NH; k0 += 64) {
        #pragma unroll
        for (int j = 0; j < 8; ++j) {
            const int r = j * 16 + (tid >> 4);
            const int c = (tid & 15) * 4;
            const int arow = tileM + r;
            float4 av = make_float4(0.f, 0.f, 0.f, 0.f);
            if (arow < M)
                av = *reinterpret_cast<const float4*>(&A[(size_t)arow * NH + k0 + c]);
            unsigned short* dst = &As[r][c];
            dst[0] = f2bf(av.x); dst[1] = f2bf(av.y);
            dst[2] = f2bf(av.z); dst[3] = f2bf(av.w);
        }
        #pragma unroll
        for (int j = 0; j < 4; ++j) {
            const int chunk = j * 256 + tid;
            const int n  = chunk >> 3;
            const int kc = (chunk & 7) * 8;
            short8v b = *reinterpret_cast<const short8v*>(
                &Bt[(size_t)(col0 + n) * NH + k0 + kc]);
            *reinterpret_cast<short8v*>(&Bs[n][kc]) = b;
        }
        __syncthreads();

        #pragma unroll
        for (int ks = 0; ks < 2; ++ks) {
            const int koff = ks * 32 + (lane >> 4) * 8;
            short8v af[4], bfr[4];
            #pragma unroll
            for (int mf = 0; mf < 4; ++mf)
                af[mf] = *reinterpret_cast<short8v*>(&As[wm + mf * 16 + (lane & 15)][koff]);
            #pragma unroll
            for (int nf = 0; nf < 4; ++nf)
                bfr[nf] = *reinterpret_cast<short8v*>(&Bs[wn + nf * 16 + (lane & 15)][koff]);
            #pragma unroll
            for (int mf = 0; mf < 4; ++mf)
                #pragma unroll
                for (int nf = 0; nf < 4; ++nf)
                    acc[mf][nf] = __builtin_amdgcn_mfma_f32_16x16x32_bf16(
                        af[mf], bfr[nf], acc[mf][nf], 0, 0, 0);
        }
        __syncthreads();
    }

    const int rgrp = (lane >> 4) * 4;
    const int cin  = lane & 15;
    #pragma unroll
    for (int mf = 0; mf < 4; ++mf) {
        #pragma unroll
        for (int r = 0; r < 4; ++r) {
            const int row = tileM + wm + mf * 16 + rgrp + r;
            if (row < M) {
                const float rs = rowscale[row];
                #pragma unroll
                for (int nf = 0; nf < 4; ++nf) {
                    const int col = col0 + wn + nf * 16 + cin;
                    C[(size_t)row * NH + col] = fmaxf(acc[mf][nf][r] + bias[col], 0.f) * rs;
                }
            }
        }
    }
}

__global__ __launch_bounds__(256) void transpose_cast_w(
    const float* __restrict__ W, unsigned short* __restrict__ Wt)
{
    __shared__ float t[32][33];
    const int bx = blockIdx.x;
    const int by = blockIdx.y;
    const int tx = threadIdx.x & 31;
    const int ty = threadIdx.x >> 5;
    #pragma unroll
    for (int j = 0; j < 32; j += 8)
        t[ty + j][tx] = W[(size_t)(by * 32 + ty + j) * NH + bx * 32 + tx];
    __syncthreads();
    #pragma unroll
    for (int j = 0; j < 32; j += 8)
        Wt[(size_t)(bx * 32 + ty + j) * NH + by * 32 + tx] = f2bf(t[tx][ty + j]);
}

// ---------------- f32 GEMM (fallback paths) ----------------
__global__ __launch_bounds__(256) void gemm_relu_scale(
    const float* __restrict__ A, const float* __restrict__ B,
    const float* __restrict__ bias, const float* __restrict__ rowscale,
    float* __restrict__ C, int M)
{
    __shared__ float As[16][68];
    __shared__ float Bs[16][64];
    const int tid = threadIdx.x;
    const int tx = tid & 15;
    const int ty = tid >> 4;
    const int tileM = blockIdx.y * 64;
    const int col0  = blockIdx.x * 64;
    const int lr  = tid >> 2;
    const int lk4 = (tid & 3) * 4;
    const int bc  = tid & 63;
    const int bk  = tid >> 6;
    float acc[4][4] = {};
    for (int k0 = 0; k0 < NH; k0 += 16) {
        const int arow = tileM + lr;
        float4 av = make_float4(0.f, 0.f, 0.f, 0.f);
        if (arow < M)
            av = *reinterpret_cast<const float4*>(&A[(size_t)arow * NH + k0 + lk4]);
        As[lk4 + 0][lr] = av.x; As[lk4 + 1][lr] = av.y;
        As[lk4 + 2][lr] = av.z; As[lk4 + 3][lr] = av.w;
        #pragma unroll
        for (int jj = 0; jj < 4; ++jj) {
            const int kk = bk + jj * 4;
            Bs[kk][bc] = B[(size_t)(k0 + kk) * NH + col0 + bc];
        }
        __syncthreads();
        #pragma unroll
        for (int kk = 0; kk < 16; ++kk) {
            float4 a = *reinterpret_cast<const float4*>(&As[kk][ty * 4]);
            float4 b = *reinterpret_cast<const float4*>(&Bs[kk][tx * 4]);
            acc[0][0] += a.x * b.x; acc[0][1] += a.x * b.y; acc[0][2] += a.x * b.z; acc[0][3] += a.x * b.w;
            acc[1][0] += a.y * b.x; acc[1][1] += a.y * b.y; acc[1][2] += a.y * b.z; acc[1][3] += a.y * b.w;
            acc[2][0] += a.z * b.x; acc[2][1] += a.z * b.y; acc[2][2] += a.z * b.z; acc[2][3] += a.z * b.w;
            acc[3][0] += a.w * b.x; acc[3][1] += a.w * b.y; acc[3][2] += a.w * b.z; acc[3][3] += a.w * b.w;
        }
        __syncthreads();
    }
    const int rbase = tileM + ty * 4;
    const int cbase = col0 + tx * 4;
    #pragma unroll
    for (int i = 0; i < 4; ++i) {
        const int row = rbase + i;
        if (row < M) {
            const float s = rowscale[row];
            float4 o;
            o.x = fmaxf(acc[i][0] + bias[cbase + 0], 0.f) * s;
            o.y = fmaxf(acc[i][1] + bias[cbase + 1], 0.f) * s;
            o.z = fmaxf(acc[i][2] + bias[cbase + 2], 0.f) * s;
            o.w = fmaxf(acc[i][3] + bias[cbase + 3], 0.f) * s;
            *reinterpret_cast<float4*>(&C[(size_t)row * NH + cbase]) = o;
        }
    }
}

// ---------------- CSR build ----------------
__global__ __launch_bounds__(256) void zero_ints(int* __restrict__ p, int n)
{
    const int i = blockIdx.x * 256 + threadIdx.x;
    if (i < n) p[i] = 0;
}

__global__ __launch_bounds__(256) void hist_kernel(
    const int* __restrict__ gi, const int* __restrict__ pi,
    int* __restrict__ e_cnt, int* __restrict__ v_cnt)
{
    const int i = blockIdx.x * 256 + threadIdx.x;
    if (i >= NI_TOT) return;
    atomicAdd(&e_cnt[gi[i]], 1);
    atomicAdd(&v_cnt[pi[i]], 1);
}

// --- 3-phase hierarchical exclusive scan (fast path) ---
// phase 1: per-block inclusive scan -> off[i+1]; block total -> bsum[b]
__global__ __launch_bounds__(256) void scan_local(
    const int* __restrict__ cnt, int* __restrict__ off, int* __restrict__ bsum, int n)
{
    __shared__ int buf[256];
    const int t = threadIdx.x;
    const int gi = blockIdx.x * 256 + t;
    int x = (gi < n) ? cnt[gi] : 0;
    buf[t] = x;
    __syncthreads();
    #pragma unroll
    for (int d = 1; d < 256; d <<= 1) {
        int y = (t >= d) ? buf[t - d] : 0;
        __syncthreads();
        buf[t] += y;
        __syncthreads();
    }
    if (gi < n) off[gi + 1] = buf[t];
    if (t == 255) bsum[blockIdx.x] = buf[255];
}

// phase 2: exclusive scan of block sums in place (nb <= 256)
__global__ __launch_bounds__(256) void scan_bsums(int* __restrict__ bsum, int nb)
{
    __shared__ int buf[256];
    const int t = threadIdx.x;
    const int x = (t < nb) ? bsum[t] : 0;
    buf[t] = x;
    __syncthreads();
    #pragma unroll
    for (int d = 1; d < 256; d <<= 1) {
        int y = (t >= d) ? buf[t - d] : 0;
        __syncthreads();
        buf[t] += y;
        __syncthreads();
    }
    if (t < nb) bsum[t] = buf[t] - x;   // inclusive - self = exclusive
}

// phase 3: add block prefix; set off[0] = 0
__global__ __launch_bounds__(256) void scan_add(
    int* __restrict__ off, const int* __restrict__ bsum, int n)
{
    const int gi = blockIdx.x * 256 + threadIdx.x;
    if (gi == 0) off[0] = 0;
    if (gi < n) off[gi + 1] += bsum[blockIdx.x];
}

// single-block scan (fallback path only)
__global__ __launch_bounds__(256) void scan_kernel(
    const int* __restrict__ cnt, int* __restrict__ off, int n)
{
    __shared__ int buf[256];
    __shared__ int carry_s;
    const int t = threadIdx.x;
    if (t == 0) { off[0] = 0; carry_s = 0; }
    __syncthreads();
    for (int base = 0; base < n; base += 256) {
        int x = (base + t < n) ? cnt[base + t] : 0;
        buf[t] = x;
        __syncthreads();
        #pragma unroll
        for (int d = 1; d < 256; d <<= 1) {
            int y = (t >= d) ? buf[t - d] : 0;
            __syncthreads();
            buf[t] += y;
            __syncthreads();
        }
        if (base + t < n) off[base + t + 1] = buf[t] + carry_s;
        __syncthreads();
        if (t == 255) carry_s += buf[255];
        __syncthreads();
    }
}

__global__ __launch_bounds__(256) void fill_kernel(
    const int* __restrict__ gi, const int* __restrict__ pi,
    const int* __restrict__ e_off, int* __restrict__ e_cur, int* __restrict__ e_list,
    const int* __restrict__ v_off, int* __restrict__ v_cur, int* __restrict__ v_list)
{
    const int i = blockIdx.x * 256 + threadIdx.x;
    if (i >= NI_TOT) return;
    const int g = gi[i];
    e_list[e_off[g] + atomicAdd(&e_cur[g], 1)] = i;
    const int p = pi[i];
    v_list[v_off[p] + atomicAdd(&v_cur[p], 1)] = i;
}

// ---------------- gather-side aggregation ----------------
__global__ __launch_bounds__(128) void agg_e_kernel(
    const float* __restrict__ e, const float* __restrict__ ve_w,
    const int* __restrict__ player_idx, const float* __restrict__ v_reg_weight,
    const int* __restrict__ e_off, const int* __restrict__ e_list,
    const float* __restrict__ e_reg_sum, float* __restrict__ out_e)
{
    const int g = blockIdx.x;
    const int c = threadIdx.x << 2;
    float4 acc = *reinterpret_cast<const float4*>(&e[(size_t)g * NH + c]);
    const int beg = e_off[g], end = e_off[g + 1];
    for (int k = beg; k < end; ++k) {
        const int   i = e_list[k];
        const int   p = player_idx[i];
        const float w = v_reg_weight[i];
        float4 x = *reinterpret_cast<const float4*>(&ve_w[(size_t)p * NH + c]);
        acc.x += w * x.x; acc.y += w * x.y; acc.z += w * x.z; acc.w += w * x.w;
    }
    const float inv = 1.0f / e_reg_sum[g];
    acc.x *= inv; acc.y *= inv; acc.z *= inv; acc.w *= inv;
    *reinterpret_cast<float4*>(&out_e[(size_t)g * NH + c]) = acc;
}

__global__ __launch_bounds__(128) void agg_v_kernel(
    const float* __restrict__ v, const float* __restrict__ v_weight,
    const float* __restrict__ ev_w,
    const int* __restrict__ game_idx, const float* __restrict__ e_reg_weight,
    const int* __restrict__ v_off, const int* __restrict__ v_list,
    const float* __restrict__ v_reg_sum, float* __restrict__ out_v)
{
    const int p = blockIdx.x;
    const int c = threadIdx.x << 2;
    const float vw = v_weight[p];
    float4 acc = *reinterpret_cast<const float4*>(&v[(size_t)p * NH + c]);
    acc.x *= vw; acc.y *= vw; acc.z *= vw; acc.w *= vw;
    const int beg = v_off[p], end = v_off[p + 1];
    for (int k = beg; k < end; ++k) {
        const int   i = v_list[k];
        const int   g = game_idx[i];
        const float w = e_reg_weight[i];
        float4 x = *reinterpret_cast<const float4*>(&ev_w[(size_t)g * NH + c]);
        acc.x += w * x.x; acc.y += w * x.y; acc.z += w * x.z; acc.w += w * x.w;
    }
    const float inv = 1.0f / v_reg_sum[p];
    acc.x *= inv; acc.y *= inv; acc.z *= inv; acc.w *= inv;
    *reinterpret_cast<float4*>(&out_v[(size_t)p * NH + c]) = acc;
}

// ---------------- atomic-path fallback kernels ----------------
__global__ __launch_bounds__(256) void scatter_add_kernel(
    const float* __restrict__ src, const int* __restrict__ gidx,
    const int* __restrict__ sidx, const float* __restrict__ regw,
    float* __restrict__ dst, int ni, int smin, int smax, int gmax)
{
    const int i = blockIdx.x * 2 + (threadIdx.x >> 7);
    if (i >= ni) return;
    const int s = sidx[i];
    if (s < smin || s >= smax) return;
    const int g = gidx[i];
    if (g < 0 || g >= gmax) return;
    const int c = (threadIdx.x & 127) << 2;
    const float w = regw[i];
    float4 val = *reinterpret_cast<const float4*>(&src[(size_t)g * NH + c]);
    float* d = &dst[(size_t)s * NH + c];
    atomicAdd(d + 0, val.x * w);
    atomicAdd(d + 1, val.y * w);
    atomicAdd(d + 2, val.z * w);
    atomicAdd(d + 3, val.w * w);
}

__global__ __launch_bounds__(256) void recompute_ev_scatter(
    const float* __restrict__ e_out, const float* __restrict__ W,
    const float* __restrict__ bias, const float* __restrict__ e_weight,
    const int* __restrict__ player_idx, const int* __restrict__ game_idx,
    const float* __restrict__ e_reg_weight, float* __restrict__ out_v, int pmin)
{
    const int i = blockIdx.x;
    const int p = player_idx[i];
    if (p < pmin || p >= NV) return;
    const int g = game_idx[i];
    if (g < 0 || g >= NE) return;
    __shared__ float eg[NH];
    const int t = threadIdx.x;
    eg[t]       = e_out[(size_t)g * NH + t];
    eg[t + 256] = e_out[(size_t)g * NH + t + 256];
    __syncthreads();
    float s0 = 0.f, s1 = 0.f;
    #pragma unroll 4
    for (int k = 0; k < NH; ++k) {
        const float ek = eg[k];
        s0 += ek * W[(size_t)k * NH + t];
        s1 += ek * W[(size_t)k * NH + t + 256];
    }
    const float ew = e_weight[g] * e_reg_weight[i];
    atomicAdd(&out_v[(size_t)p * NH + t],       fmaxf(s0 + bias[t], 0.f) * ew);
    atomicAdd(&out_v[(size_t)p * NH + t + 256], fmaxf(s1 + bias[t + 256], 0.f) * ew);
}

__global__ __launch_bounds__(256) void init_copy(
    const float* __restrict__ src, float* __restrict__ dst, int n4)
{
    const int i = blockIdx.x * 256 + threadIdx.x;
    if (i < n4)
        reinterpret_cast<float4*>(dst)[i] = reinterpret_cast<const float4*>(src)[i];
}

__global__ __launch_bounds__(256) void init_scale_rows(
    const float* __restrict__ src, const float* __restrict__ w,
    float* __restrict__ dst, int n4)
{
    const int i = blockIdx.x * 256 + threadIdx.x;
    if (i >= n4) return;
    const int row = i >> 7;
    const float s = w[row];
    float4 v = reinterpret_cast<const float4*>(src)[i];
    v.x *= s; v.y *= s; v.z *= s; v.w *= s;
    reinterpret_cast<float4*>(dst)[i] = v;
}

__global__ __launch_bounds__(256) void div_rows(
    const float* __restrict__ rs, float* __restrict__ x, int n4)
{
    const int i = blockIdx.x * 256 + threadIdx.x;
    if (i >= n4) return;
    const int row = i >> 7;
    const float inv = 1.0f / rs[row];
    float4 v = reinterpret_cast<float4*>(x)[i];
    v.x *= inv; v.y *= inv; v.z *= inv; v.w *= inv;
    reinterpret_cast<float4*>(x)[i] = v;
}

extern "C" void kernel_launch(void* const* d_in, const int* in_sizes, int n_in,
                              void* d_out, int out_size, void* d_ws, size_t ws_size,
                              hipStream_t stream) {
    const float* v            = (const float*)d_in[0];
    const float* e            = (const float*)d_in[1];
    const int*   player_idx   = (const int*)d_in[2];
    const int*   game_idx     = (const int*)d_in[3];
    const float* W_v2e        = (const float*)d_in[5];
    const float* W_e2v        = (const float*)d_in[6];
    const float* b_v          = (const float*)d_in[7];
    const float* b_e          = (const float*)d_in[8];

    const float* a9  = (const float*)d_in[9];
    const float* a10 = (const float*)d_in[10];
    const float* v_weight = (in_sizes[9]  == NV) ? a9  : a10;
    const float* e_weight = (in_sizes[9]  == NV) ? a10 : a9;
    const float* v_reg_weight = (const float*)d_in[11];
    const float* e_reg_weight = (const float*)d_in[12];
    const float* a13 = (const float*)d_in[13];
    const float* a14 = (const float*)d_in[14];
    const float* e_reg_sum = (in_sizes[13] == NE) ? a13 : a14;
    const float* v_reg_sum = (in_sizes[13] == NE) ? a14 : a13;

    float* out_v = (float*)d_out;
    float* out_e = (float*)d_out + (size_t)NV * NH;

    const dim3 blk(256);
    const int NB_E = (NE + 255) / 256;   // 40
    const int NB_V = (NV + 255) / 256;   // 196

    // ---- ws layout ----
    float* ev_w = (float*)d_ws;
    int* e_cnt  = (int*)((char*)d_ws + (size_t)NE * NH * sizeof(float));
    int* v_cnt  = e_cnt + NE;
    int* e_cur  = v_cnt + NV;
    int* v_cur  = e_cur + NE;
    int* e_off  = v_cur + NV;
    int* v_off  = e_off + NE + 1;
    int* e_list = v_off + NV + 1;
    int* v_list = e_list + NI_TOT;
    int* e_bsum = v_list + NI_TOT;      // NB_E
    int* v_bsum = e_bsum + NB_E;        // NB_V
    unsigned short* Wt1 = (unsigned short*)(v_bsum + NB_V);
    unsigned short* Wt2 = Wt1 + (size_t)NH * NH;
    const size_t csr_need  = (size_t)((char*)(v_list + NI_TOT) - (char*)d_ws);
    const size_t mfma_need = (size_t)((char*)(Wt2 + (size_t)NH * NH) - (char*)d_ws);

    if (ws_size >= mfma_need && d_ws != nullptr) {
        // ---------- bf16-MFMA + CSR path ----------
        transpose_cast_w<<<dim3(16, 16), blk, 0, stream>>>(W_v2e, Wt1);
        transpose_cast_w<<<dim3(16, 16), blk, 0, stream>>>(W_e2v, Wt2);
        const int nz = 2 * (NE + NV);
        zero_ints<<<(nz + 255) / 256, blk, 0, stream>>>(e_cnt, nz);
        hist_kernel<<<(NI_TOT + 255) / 256, blk, 0, stream>>>(
            game_idx, player_idx, e_cnt, v_cnt);
        // hierarchical scans
        scan_local<<<NB_E, blk, 0, stream>>>(e_cnt, e_off, e_bsum, NE);
        scan_bsums<<<1, blk, 0, stream>>>(e_bsum, NB_E);
        scan_add<<<NB_E, blk, 0, stream>>>(e_off, e_bsum, NE);
        scan_local<<<NB_V, blk, 0, stream>>>(v_cnt, v_off, v_bsum, NV);
        scan_bsums<<<1, blk, 0, stream>>>(v_bsum, NB_V);
        scan_add<<<NB_V, blk, 0, stream>>>(v_off, v_bsum, NV);
        fill_kernel<<<(NI_TOT + 255) / 256, blk, 0, stream>>>(
            game_idx, player_idx, e_off, e_cur, e_list, v_off, v_cur, v_list);
        // ve_w -> out_v (temp)
        gemm_mfma_relu_scale<<<dim3(NH / 128, (NV + 127) / 128), blk, 0, stream>>>(
            v, Wt1, b_v, v_weight, out_v, NV);
        agg_e_kernel<<<NE, dim3(128), 0, stream>>>(
            e, out_v, player_idx, v_reg_weight, e_off, e_list, e_reg_sum, out_e);
        gemm_mfma_relu_scale<<<dim3(NH / 128, (NE + 127) / 128), blk, 0, stream>>>(
            out_e, Wt2, b_e, e_weight, ev_w, NE);
        agg_v_kernel<<<NV, dim3(128), 0, stream>>>(
            v, v_weight, ev_w, game_idx, e_reg_weight, v_off, v_list,
            v_reg_sum, out_v);
        return;
    }

    if (ws_size >= csr_need && d_ws != nullptr) {
        // ---------- f32 + CSR path ----------
        gemm_relu_scale<<<dim3(NH / 64, (NV + 63) / 64), blk, 0, stream>>>(
            v, W_v2e, b_v, v_weight, out_v, NV);
        const int nz = 2 * (NE + NV);
        zero_ints<<<(nz + 255) / 256, blk, 0, stream>>>(e_cnt, nz);
        hist_kernel<<<(NI_TOT + 255) / 256, blk, 0, stream>>>(
            game_idx, player_idx, e_cnt, v_cnt);
        scan_kernel<<<1, blk, 0, stream>>>(e_cnt, e_off, NE);
        scan_kernel<<<1, blk, 0, stream>>>(v_cnt, v_off, NV);
        fill_kernel<<<(NI_TOT + 255) / 256, blk, 0, stream>>>(
            game_idx, player_idx, e_off, e_cur, e_list, v_off, v_cur, v_list);
        agg_e_kernel<<<NE, dim3(128), 0, stream>>>(
            e, out_v, player_idx, v_reg_weight, e_off, e_list, e_reg_sum, out_e);
        gemm_relu_scale<<<dim3(NH / 64, (NE + 63) / 64), blk, 0, stream>>>(
            out_e, W_e2v, b_e, e_weight, ev_w, NE);
        agg_v_kernel<<<NV, dim3(128), 0, stream>>>(
            v, v_weight, ev_w, game_idx, e_reg_weight, v_off, v_list,
            v_reg_sum, out_v);
        return;
    }

    // ---------- atomic fallback ----------
    const size_t evw_bytes = (size_t)NE * NH * sizeof(float);
    const bool big_ws = (ws_size >= evw_bytes) && (d_ws != nullptr);
    float* ev_w2 = big_ws ? (float*)d_ws : (out_v + (size_t)PB * NH);
    const int pb = big_ws ? NV : PB;
    const int n4_e = NE * NH / 4;

    gemm_relu_scale<<<dim3(NH / 64, (NV + 63) / 64), blk, 0, stream>>>(
        v, W_v2e, b_v, v_weight, out_v, NV);
    init_copy<<<(n4_e + 255) / 256, blk, 0, stream>>>(e, out_e, n4_e);
    scatter_add_kernel<<<(NI_TOT + 1) / 2, blk, 0, stream>>>(
        out_v, player_idx, game_idx, v_reg_weight, out_e, NI_TOT, 0, NE, NV);
    div_rows<<<(n4_e + 255) / 256, blk, 0, stream>>>(e_reg_sum, out_e, n4_e);
    gemm_relu_scale<<<dim3(NH / 64, (NE + 63) / 64), blk, 0, stream>>>(
        out_e, W_e2v, b_e, e_weight, ev_w2, NE);
    {
        const int n4 = pb * NH / 4;
        init_scale_rows<<<(n4 + 255) / 256, blk, 0, stream>>>(v, v_weight, out_v, n4);
    }
    scatter_add_kernel<<<(NI_TOT + 1) / 2, blk, 0, stream>>>(
        ev_w2, game_idx, player_idx, e_reg_weight, out_v, NI_TOT, 0, pb, NE);
    {
        const int n4 = pb * NH / 4;
        div_rows<<<(n4 + 255) / 256, blk, 0, stream>>>(v_reg_sum, out_v, n4);
    }
    if (!big_ws) {
        const int n4t = (NV - PB) * NH / 4;
        init_scale_rows<<<(n4t + 255) / 256, blk, 0, stream>>>(
            v + (size_t)PB * NH, v_weight + PB, out_v + (size_t)PB * NH, n4t);
        recompute_ev_scatter<<<NI_TOT, blk, 0, stream>>>(
            out_e, W_e2v, b_e, e_weight, player_idx, game_idx, e_reg_weight,
            out_v, PB);
        div_rows<<<(n4t + 255) / 256, blk, 0, stream>>>(
            v_reg_sum + PB, out_v + (size_t)PB * NH, n4t);
    }
}